// Round 10
// baseline (11305.315 us; speedup 1.0000x reference)
//
#include <hip/hip_runtime.h>

// Problem constants: B=4, T=2048, D=1024, H=16, HD=64
// MODEL (r0-r9, all observations explained): inputs all f32 (listing order),
// OUTPUT F32 [B,T,D] (r9 probe refuted bf16-output: low-half ushort probe was
// invisible). Math: torch convention x@W.T+b, rotate-half RoPE pos=t+1,
// causal softmax(QK^T/8)V, O-proj — certified by r6 on-device brute check.
#define BB 4
#define TT 2048
#define DD 1024
#define HH 16
#define HD 64

__device__ __forceinline__ float b2f(unsigned short u) {
    return __uint_as_float(((unsigned int)u) << 16);
}
__device__ __forceinline__ unsigned short f2b(float f) {
    unsigned int i = __float_as_uint(f);
    unsigned int r = i + 0x7fffu + ((i >> 16) & 1u);   // round-to-nearest-even
    return (unsigned short)(r >> 16);
}

// ---------------------------------------------------------------------------
// Tiled GEMM (torch convention): out[n,j] = sum_k A[n,k] * W[j,k] + bias[j]
// A: [N x K] f32 row-major; W: [J x K] f32 row-major.
// mode==1: bf16 scatter out[((b*H+h)*T+t)*64+dd]   (q/k/v staging)
// mode==0: f32 flat   out[n*J + j]                  (final output)
// Block: 256 threads (16x16), 64x64 tile, 4x4 acc/thread, BK=32, f32 accum.
// ---------------------------------------------------------------------------
__global__ __launch_bounds__(256) void gemm_f32(
    const float* __restrict__ A, const float* __restrict__ W,
    const float* __restrict__ bias, void* __restrict__ outp,
    int N, int K, int J, int mode)
{
    __shared__ float As[32][68];
    __shared__ float Ws[32][68];

    const int tid = threadIdx.x;
    const int tx = tid & 15, ty = tid >> 4;
    const int n0 = blockIdx.y * 64;
    const int j0 = blockIdx.x * 64;
    const int tx4 = tx * 4, ty4 = ty * 4;

    float acc[4][4] = {};

    for (int k0 = 0; k0 < K; k0 += 32) {
        __syncthreads();
#pragma unroll
        for (int vv = 0; vv < 2; vv++) {
            int vi = tid + vv * 256;       // 0..511
            int r = vi >> 3;               // row 0..63
            int c = (vi & 7) << 2;         // k-offset 0..28
            float4 av = *(const float4*)(A + (size_t)(n0 + r) * K + (k0 + c));
            As[c + 0][r] = av.x; As[c + 1][r] = av.y;
            As[c + 2][r] = av.z; As[c + 3][r] = av.w;
            float4 wv = *(const float4*)(W + (size_t)(j0 + r) * K + (k0 + c));
            Ws[c + 0][r] = wv.x; Ws[c + 1][r] = wv.y;
            Ws[c + 2][r] = wv.z; Ws[c + 3][r] = wv.w;
        }
        __syncthreads();
#pragma unroll
        for (int kk = 0; kk < 32; kk++) {
            float4 av = *(const float4*)&As[kk][ty4];
            float4 wv = *(const float4*)&Ws[kk][tx4];
            acc[0][0] += av.x * wv.x; acc[0][1] += av.x * wv.y;
            acc[0][2] += av.x * wv.z; acc[0][3] += av.x * wv.w;
            acc[1][0] += av.y * wv.x; acc[1][1] += av.y * wv.y;
            acc[1][2] += av.y * wv.z; acc[1][3] += av.y * wv.w;
            acc[2][0] += av.z * wv.x; acc[2][1] += av.z * wv.y;
            acc[2][2] += av.z * wv.z; acc[2][3] += av.z * wv.w;
            acc[3][0] += av.w * wv.x; acc[3][1] += av.w * wv.y;
            acc[3][2] += av.w * wv.z; acc[3][3] += av.w * wv.w;
        }
    }

    float bb4[4];
#pragma unroll
    for (int jj = 0; jj < 4; jj++) bb4[jj] = bias[j0 + tx4 + jj];

#pragma unroll
    for (int i = 0; i < 4; i++) {
        int n = n0 + ty4 + i;
#pragma unroll
        for (int jj = 0; jj < 4; jj++) {
            int j = j0 + tx4 + jj;
            float v = acc[i][jj] + bb4[jj];
            if (mode == 0) {
                ((float*)outp)[(size_t)n * J + j] = v;
            } else {
                int b = n >> 11, t = n & (TT - 1);
                int h = j >> 6, dd = j & 63;
                ((unsigned short*)outp)[(((size_t)(b * HH + h) * TT + t) << 6) + dd] = f2b(v);
            }
        }
    }
}

// ---------------------------------------------------------------------------
// RoPE (rotate-half) in-place on [B,H,T,64] bf16.
// Pair (i, i+32), i in [0,32); theta_i = 10000^(-i/32); pos = t+1.
// ---------------------------------------------------------------------------
__global__ __launch_bounds__(256) void rope_kernel(unsigned short* __restrict__ buf)
{
    int idx = blockIdx.x * 256 + threadIdx.x;    // B*H*T*32 total
    int i = idx & 31;
    int t = (idx >> 5) & (TT - 1);
    int bh = idx >> 16;
    size_t base = ((size_t)bh * TT + t) * 64;
    float x1 = b2f(buf[base + i]);
    float x2 = b2f(buf[base + 32 + i]);
    float theta = exp2f(-(float)i * (13.287712379549449f / 32.0f));
    float ang = (float)(t + 1) * theta;
    float s = sinf(ang), c = cosf(ang);
    buf[base + i]       = f2b(x1 * c - x2 * s);
    buf[base + 32 + i]  = f2b(x2 * c + x1 * s);
}

// ---------------------------------------------------------------------------
// Causal attention, one block (256 threads) per (b,h,t).
// q,k,v bf16 [B,H,T,64]; writes FLOAT32 [B,T,D] (into d_out).
// Two-pass softmax with scores in LDS, f32 accumulation.
// ---------------------------------------------------------------------------
__global__ __launch_bounds__(256) void attn_kernel(
    const unsigned short* __restrict__ q,
    const unsigned short* __restrict__ k,
    const unsigned short* __restrict__ v,
    float* __restrict__ aout)
{
    __shared__ float qs[64];
    __shared__ float scores[TT];
    __shared__ float red[8];
    __shared__ float pacc[4][64];

    const int t = blockIdx.x, h = blockIdx.y, b = blockIdx.z;
    const int tid = threadIdx.x;
    const int bh = b * HH + h;
    const unsigned short* Kp = k + (size_t)bh * TT * 64;
    const unsigned short* Vp = v + (size_t)bh * TT * 64;
    const unsigned short* Qp = q + ((size_t)bh * TT + t) * 64;

    if (tid < 64) qs[tid] = b2f(Qp[tid]);
    __syncthreads();

    const int nk = t + 1;

    for (int j = tid; j < nk; j += 256) {
        const ushort4* kr = (const ushort4*)(Kp + (size_t)j * 64);
        float s = 0.f;
#pragma unroll
        for (int d4 = 0; d4 < 16; d4++) {
            ushort4 kv = kr[d4];
            s += qs[d4 * 4 + 0] * b2f(kv.x);
            s += qs[d4 * 4 + 1] * b2f(kv.y);
            s += qs[d4 * 4 + 2] * b2f(kv.z);
            s += qs[d4 * 4 + 3] * b2f(kv.w);
        }
        scores[j] = s * 0.125f;   // 1/sqrt(64)
    }
    __syncthreads();

    float m = -1e30f;
    for (int j = tid; j < nk; j += 256) m = fmaxf(m, scores[j]);
#pragma unroll
    for (int off = 32; off > 0; off >>= 1) m = fmaxf(m, __shfl_down(m, off));
    if ((tid & 63) == 0) red[tid >> 6] = m;
    __syncthreads();
    const float rowmax = fmaxf(fmaxf(red[0], red[1]), fmaxf(red[2], red[3]));

    float l = 0.f;
    for (int j = tid; j < nk; j += 256) {
        float p = __expf(scores[j] - rowmax);
        scores[j] = p;
        l += p;
    }
#pragma unroll
    for (int off = 32; off > 0; off >>= 1) l += __shfl_down(l, off);
    if ((tid & 63) == 0) red[4 + (tid >> 6)] = l;
    __syncthreads();
    const float denom = red[4] + red[5] + red[6] + red[7];

    const int d = tid & 63, g = tid >> 6;
    float acc = 0.f;
    for (int j = g; j < nk; j += 4)
        acc += scores[j] * b2f(Vp[(size_t)j * 64 + d]);
    pacc[g][d] = acc;
    __syncthreads();

    if (tid < 64) {
        float o = (pacc[0][tid] + pacc[1][tid] + pacc[2][tid] + pacc[3][tid]) / denom;
        aout[((size_t)(b * TT + t)) * DD + h * 64 + tid] = o;
    }
}

// ---------------------------------------------------------------------------
extern "C" void kernel_launch(void* const* d_in, const int* in_sizes, int n_in,
                              void* d_out, int out_size, void* d_ws, size_t ws_size,
                              hipStream_t stream)
{
    const float* x  = (const float*)d_in[0];
    const float* Wq = (const float*)d_in[1];
    const float* bq = (const float*)d_in[2];
    const float* Wk = (const float*)d_in[3];
    const float* bk = (const float*)d_in[4];
    const float* Wv = (const float*)d_in[5];
    const float* bv = (const float*)d_in[6];
    const float* Wo = (const float*)d_in[7];
    const float* bo = (const float*)d_in[8];
    float* out = (float*)d_out;                     // FLOAT32 output [B,T,D]

    const size_t NE = (size_t)BB * HH * TT * HD;    // 8388608 elements
    // ws: q/k/v bf16 (50.3 MB). After attn, q+k region (33.6 MB) is dead and
    // is reused as the f32 O-projection result buffer.
    unsigned short* q    = (unsigned short*)d_ws;
    unsigned short* kbuf = q + NE;
    unsigned short* vbuf = kbuf + NE;
    float* res = (float*)d_ws;                      // overlays dead q+k

    const int N = BB * TT;                          // 8192 tokens
    dim3 blk(256);
    dim3 gp(DD / 64, N / 64);                       // (16, 128)

    gemm_f32<<<gp, blk, 0, stream>>>(x, Wq, bq, q,    N, DD, DD, 1);
    gemm_f32<<<gp, blk, 0, stream>>>(x, Wk, bk, kbuf, N, DD, DD, 1);
    gemm_f32<<<gp, blk, 0, stream>>>(x, Wv, bv, vbuf, N, DD, DD, 1);

    int rope_total = BB * HH * TT * 32;             // 4194304
    rope_kernel<<<rope_total / 256, 256, 0, stream>>>(q);
    rope_kernel<<<rope_total / 256, 256, 0, stream>>>(kbuf);

    // attention output (f32 [B,T,D]) straight into d_out
    attn_kernel<<<dim3(TT, HH, BB), blk, 0, stream>>>(q, kbuf, vbuf, out);

    // O-projection: A = d_out (f32), result f32 -> res (dead q+k region)
    gemm_f32<<<gp, blk, 0, stream>>>(out, Wo, bo, res, N, DD, DD, 0);

    // copy result back to d_out
    hipMemcpyAsync(out, res, (size_t)N * DD * sizeof(float),
                   hipMemcpyDeviceToDevice, stream);
}